// Round 1
// baseline (405.678 us; speedup 1.0000x reference)
//
#include <hip/hip_runtime.h>

// GraphAttentionLayer: out = softmax(mask(beta * cos_sim(x,x), adj)) @ x
// N=8192 nodes, D=128 features, adjacency density 0.005 (~41 neighbors/row).
//
// Strategy: the -1e9 mask makes softmax rows sparse (exp underflows to 0.0f
// exactly for non-neighbors, matching the fp32 reference). |score| < beta < 1
// so exp never over/underflows -> no max-subtraction pass needed (softmax is
// shift-invariant). One wave per row: scan adj row coalesced, ballot-compact
// nonzero column indices into LDS, compute scores lane-parallel, accumulate
// weighted sum coalesced. Memory floor = reading adj (268 MB) ~ 44 us.

#define GN 8192
#define GD 128
#define WPB 4          // waves (rows) per 256-thread block
#define CAP 512        // flush threshold for index buffer
#define BUF 520        // CAP + 8 pad slack

__global__ __launch_bounds__(256) void norms_kernel(
    const float* __restrict__ x, float* __restrict__ norms) {
    int wid = threadIdx.x >> 6, lane = threadIdx.x & 63;
    int row = blockIdx.x * WPB + wid;
    const float2* xr = (const float2*)(x + (size_t)row * GD);
    float2 v = xr[lane];
    float s = v.x * v.x + v.y * v.y;
    #pragma unroll
    for (int m = 32; m; m >>= 1) s += __shfl_xor(s, m, 64);
    if (lane == 0) norms[row] = sqrtf(s);
}

__global__ __launch_bounds__(256) void gat_kernel(
    const float* __restrict__ x, const float* __restrict__ adj,
    const float* __restrict__ beta_p, const float* __restrict__ norms,
    float* __restrict__ out) {
    __shared__ float4 xi4[WPB][GD / 4];
    __shared__ int    idxb[WPB][BUF];
    __shared__ float  pb[WPB][BUF];

    int wid = threadIdx.x >> 6, lane = threadIdx.x & 63;
    int row = blockIdx.x * WPB + wid;
    float4* myxi = xi4[wid];
    int*    myidx = idxb[wid];
    float*  myp = pb[wid];

    const float* xr = x + (size_t)row * GD;
    if (lane < 32) myxi[lane] = ((const float4*)xr)[lane];
    float beta = beta_p[0];
    float ni = norms[row];
    const float* arow = adj + (size_t)row * GN;

    float2 acc = {0.f, 0.f};
    float lpart = 0.f;   // per-lane partial of softmax denominator
    int cnt = 0;         // wave-uniform (derived from ballots)
    unsigned long long below = (1ULL << lane) - 1ULL;
    __builtin_amdgcn_wave_barrier();

    for (int chunk = 0; chunk < 32; ++chunk) {
        int col0 = chunk * 256 + lane * 4;
        float4 a = *(const float4*)(arow + col0);

        // ballot-based compaction (no atomics); cnt stays wave-uniform
        {
            bool nz = (a.x != 0.f);
            unsigned long long m = __ballot(nz);
            if (nz) myidx[cnt + __popcll(m & below)] = col0 + 0;
            cnt += __popcll(m);
        }
        {
            bool nz = (a.y != 0.f);
            unsigned long long m = __ballot(nz);
            if (nz) myidx[cnt + __popcll(m & below)] = col0 + 1;
            cnt += __popcll(m);
        }
        {
            bool nz = (a.z != 0.f);
            unsigned long long m = __ballot(nz);
            if (nz) myidx[cnt + __popcll(m & below)] = col0 + 2;
            cnt += __popcll(m);
        }
        {
            bool nz = (a.w != 0.f);
            unsigned long long m = __ballot(nz);
            if (nz) myidx[cnt + __popcll(m & below)] = col0 + 3;
            cnt += __popcll(m);
        }

        if (chunk == 31 || cnt > CAP - 256) {
            __builtin_amdgcn_wave_barrier();
            // Phase A: lane k computes score for neighbor k (full 128-dot)
            float lp = 0.f;
            for (int b = 0; b < cnt; b += 64) {
                int k = b + lane;
                float p = 0.f;
                if (k < cnt) {
                    int j = myidx[k];
                    const float4* xj = (const float4*)(x + (size_t)j * GD);
                    float dot = 0.f;
                    #pragma unroll 8
                    for (int t = 0; t < GD / 4; ++t) {
                        float4 v = xj[t];
                        float4 u = myxi[t];   // LDS broadcast, conflict-free
                        dot += v.x * u.x + v.y * u.y + v.z * u.z + v.w * u.w;
                    }
                    float nj = norms[j];
                    float s = beta * dot / (ni * nj + 1e-7f);
                    p = expf(s);
                    myp[k] = p;
                }
                lp += p;
            }
            lpart += lp;
            if (lane < 8) { myp[cnt + lane] = 0.f; myidx[cnt + lane] = 0; }
            __builtin_amdgcn_wave_barrier();

            // Phase B: coalesced weighted accumulation, unroll-8 to overlap
            // the (L2-resident) x loads
            int cn = (cnt + 7) & ~7;
            for (int k = 0; k < cn; k += 8) {
                float pp[8];
                float2 vv[8];
                #pragma unroll
                for (int u = 0; u < 8; ++u) {
                    int j = myidx[k + u];       // LDS broadcast
                    pp[u] = myp[k + u];         // LDS broadcast
                    vv[u] = *(const float2*)(x + (size_t)j * GD + lane * 2);
                }
                #pragma unroll
                for (int u = 0; u < 8; ++u) {
                    acc.x += pp[u] * vv[u].x;
                    acc.y += pp[u] * vv[u].y;
                }
            }
            cnt = 0;
            __builtin_amdgcn_wave_barrier();
        }
    }

    // softmax denominator: reduce per-lane partials across the wave
    float l = lpart;
    #pragma unroll
    for (int m = 32; m; m >>= 1) l += __shfl_xor(l, m, 64);
    float inv = 1.0f / l;
    float2 o = {acc.x * inv, acc.y * inv};
    *(float2*)(out + (size_t)row * GD + lane * 2) = o;
}

extern "C" void kernel_launch(void* const* d_in, const int* in_sizes, int n_in,
                              void* d_out, int out_size, void* d_ws, size_t ws_size,
                              hipStream_t stream) {
    const float* x    = (const float*)d_in[0];
    const float* adj  = (const float*)d_in[1];
    const float* beta = (const float*)d_in[2];
    float* out   = (float*)d_out;
    float* norms = (float*)d_ws;   // 8192 floats = 32 KB

    norms_kernel<<<GN / WPB, 256, 0, stream>>>(x, norms);
    gat_kernel<<<GN / WPB, 256, 0, stream>>>(x, adj, beta, norms, out);
}

// Round 2
// 366.126 us; speedup vs baseline: 1.1080x; 1.1080x over previous
//
#include <hip/hip_runtime.h>

// GraphAttentionLayer: out = softmax(mask(beta * cos_sim(x,x), adj)) @ x
// N=8192, D=128, density 0.005 (~41 neighbors/row, self-loops included).
//
// Sparse formulation: exp(-1e9) == 0.0f exactly in fp32, so non-neighbors
// contribute nothing. |score| < beta < 1 -> exp never over/underflows ->
// no max pass (softmax shift-invariance). One wave per row:
//   1. stream the 32 KB adj row (nontemporal, prefetched), ballot-compact
//      nonzero column indices into LDS;
//   2. per neighbor j (wave-uniform): coalesced load of x[j] (float2/lane),
//      dot vs register-held x_i, butterfly reduce, p = exp(score); reuse the
//      SAME v registers for acc += p*v  (no second gather pass).
// Memory floor = adj read 268 MB ~ 44 us @ 6.3 TB/s; x stays L2/L3-resident
// because adj loads are nontemporal.

#define GN 8192
#define GD 128
#define WPB 4            // waves (rows) per 256-thread block
#define CAP 1024         // flush threshold headroom (mean nnz ~41, max ~80)
#define BUF (CAP + 8)

typedef float f32x4 __attribute__((ext_vector_type(4)));

__global__ __launch_bounds__(256) void norms_kernel(
    const float* __restrict__ x, float* __restrict__ norms) {
    int wid = threadIdx.x >> 6, lane = threadIdx.x & 63;
    int row = blockIdx.x * WPB + wid;
    const float2* xr = (const float2*)(x + (size_t)row * GD);
    float2 v = xr[lane];
    float s = v.x * v.x + v.y * v.y;
    #pragma unroll
    for (int m = 32; m; m >>= 1) s += __shfl_xor(s, m, 64);
    if (lane == 0) norms[row] = sqrtf(s);
}

__global__ __launch_bounds__(256, 8) void gat_kernel(
    const float* __restrict__ x, const float* __restrict__ adj,
    const float* __restrict__ beta_p, const float* __restrict__ norms,
    float* __restrict__ out) {
    __shared__ int idxb[WPB][BUF];

    int wid = threadIdx.x >> 6, lane = threadIdx.x & 63;
    int row = blockIdx.x * WPB + wid;
    int* myidx = idxb[wid];

    // x_i held in registers: float2 per lane (coalesced load)
    float2 u = *(const float2*)(x + (size_t)row * GD + lane * 2);
    float beta = beta_p[0];
    float ni = norms[row];
    const float* arow = adj + (size_t)row * GN;

    float2 acc = {0.f, 0.f};
    float denom = 0.f;            // wave-uniform (butterfly sums are bit-identical)
    int cnt = 0;                  // wave-uniform (from ballots)
    unsigned long long below = (1ULL << lane) - 1ULL;

    // prefetched nontemporal adj stream: 1 KB per wave-instruction
    f32x4 a = __builtin_nontemporal_load((const f32x4*)(arow + lane * 4));

    for (int chunk = 0; chunk < 32; ++chunk) {
        int nc = (chunk + 1 < 32) ? chunk + 1 : 31;
        f32x4 an = __builtin_nontemporal_load(
            (const f32x4*)(arow + nc * 256 + lane * 4));
        int col0 = chunk * 256 + lane * 4;

        // ballot-based compaction (no atomics); cnt stays wave-uniform
        #pragma unroll
        for (int c = 0; c < 4; ++c) {
            bool nz = (a[c] != 0.f);
            unsigned long long m = __ballot(nz);
            if (nz) myidx[cnt + __popcll(m & below)] = col0 + c;
            cnt += __popcll(m);
        }
        a = an;

        if (chunk == 31 || cnt > CAP - 256) {
            // pad with sentinels so the unroll-4 tail reads valid indices
            if (lane < 4) myidx[cnt + lane] = row;
            __builtin_amdgcn_wave_barrier();

            int cn = cnt;  // uniform
            for (int k = 0; k < cn; k += 4) {
                int jj[4]; float2 v[4]; float d[4];
                #pragma unroll
                for (int t = 0; t < 4; ++t) jj[t] = myidx[k + t];  // LDS broadcast
                #pragma unroll
                for (int t = 0; t < 4; ++t)
                    v[t] = *(const float2*)(x + (size_t)jj[t] * GD + lane * 2);
                #pragma unroll
                for (int t = 0; t < 4; ++t)
                    d[t] = v[t].x * u.x + v[t].y * u.y;
                // 4 independent butterfly reductions, interleaved for ILP
                #pragma unroll
                for (int m = 32; m; m >>= 1) {
                    #pragma unroll
                    for (int t = 0; t < 4; ++t) d[t] += __shfl_xor(d[t], m, 64);
                }
                #pragma unroll
                for (int t = 0; t < 4; ++t) {
                    float nj = norms[jj[t]];   // uniform address -> broadcast
                    float s = beta * d[t] * __builtin_amdgcn_rcpf(ni * nj + 1e-7f);
                    float p = __expf(s);
                    p = (k + t < cn) ? p : 0.f;
                    acc.x += p * v[t].x;
                    acc.y += p * v[t].y;
                    denom += p;
                }
            }
            cnt = 0;
            __builtin_amdgcn_wave_barrier();
        }
    }

    float inv = 1.0f / denom;     // denom uniform across lanes
    float2 o = {acc.x * inv, acc.y * inv};
    *(float2*)(out + (size_t)row * GD + lane * 2) = o;
}

extern "C" void kernel_launch(void* const* d_in, const int* in_sizes, int n_in,
                              void* d_out, int out_size, void* d_ws, size_t ws_size,
                              hipStream_t stream) {
    const float* x    = (const float*)d_in[0];
    const float* adj  = (const float*)d_in[1];
    const float* beta = (const float*)d_in[2];
    float* out   = (float*)d_out;
    float* norms = (float*)d_ws;   // 8192 floats = 32 KB

    norms_kernel<<<GN / WPB, 256, 0, stream>>>(x, norms);
    gat_kernel<<<GN / WPB, 256, 0, stream>>>(x, adj, beta, norms, out);
}